// Round 11
// baseline (274.949 us; speedup 1.0000x reference)
//
#include <hip/hip_runtime.h>
#include <type_traits>

#define NQ 10
#define N_DEPTH 5
#define DIM 1024
#define BATCH 16384
#define IN_DIM 784
#define NGATES 50
#define KPAD 800      // GEMM K extent (25*32); Xb/W2T cols >=784 are zero
#define KALLOC 832    // W2 row allocation (13*64 transpose tiles)
#define NK 25         // K-steps of 32

typedef float f32x2 __attribute__((ext_vector_type(2)));
typedef float f32x4 __attribute__((ext_vector_type(4)));
typedef short bf16x8 __attribute__((ext_vector_type(8)));
typedef unsigned u32x4 __attribute__((ext_vector_type(4)));

// ---------------------------------------------------------------------------
// Compile-time mask tables: CNOTs absorbed into GF(2)-linear index transform.
// ---------------------------------------------------------------------------
struct MaskTab {
  unsigned v[NGATES];
  unsigned p[NGATES];
  unsigned vz0, vz1;
};

constexpr MaskTab make_masks() {
  MaskTab t{};
  unsigned v[NQ], p[NQ];
  for (int i = 0; i < NQ; ++i) { v[i] = 1u << (9 - i); p[i] = 1u << (9 - i); }
  for (int d = 0; d < N_DEPTH; ++d) {
    for (int i = 0; i < NQ; ++i) {
      int c = i, tt = (i + 1) % NQ;
      v[tt] ^= v[c];
      p[c]  ^= p[tt];
    }
    for (int i = 0; i < NQ; ++i) {
      t.v[d * NQ + i] = v[i];
      t.p[d * NQ + i] = p[i];
    }
  }
  t.vz0 = v[0];
  t.vz1 = v[1];
  return t;
}

constexpr MaskTab MT = make_masks();
__constant__ MaskTab d_MT = make_masks();

// d = co*o + cp*q (complex), packed (re,im); 4 VOP3P instrs (verified r2-r10).
__device__ __forceinline__ f32x2 ampfma(f32x2 o, f32x2 q, f32x2 co, f32x2 cp) {
  f32x2 d;
  asm("v_pk_mul_f32 %0, %2, %1 op_sel:[0,0] op_sel_hi:[0,1]\n\t"
      "v_pk_fma_f32 %0, %2, %1, %0 op_sel:[1,1,0] op_sel_hi:[1,0,1] neg_lo:[1,0,0]\n\t"
      "v_pk_fma_f32 %0, %3, %4, %0 op_sel:[0,0,0] op_sel_hi:[0,1,1]\n\t"
      "v_pk_fma_f32 %0, %3, %4, %0 op_sel:[1,1,0] op_sel_hi:[1,0,1] neg_lo:[1,0,0]"
      : "=&v"(d)
      : "v"(o), "v"(co), "v"(cp), "v"(q));
  return d;
}

__device__ __forceinline__ float fxor(float x, unsigned m) {
  return __uint_as_float(__float_as_uint(x) ^ m);
}

__device__ __forceinline__ unsigned bf16pack(float lo, float hi) {
  unsigned a = __float_as_uint(lo), b = __float_as_uint(hi);
  unsigned ra = (a + 0x7fffu + ((a >> 16) & 1u)) >> 16;   // RNE
  unsigned rb = (b + 0x7fffu + ((b >> 16) & 1u)) >> 16;
  return (ra & 0xffffu) | (rb << 16);
}

__device__ __forceinline__ unsigned cvtpk(float a, float b) {
  unsigned d;
  asm("v_cvt_pk_bf16_f32 %0, %1, %2" : "=v"(d) : "v"(a), "v"(b));
  return d;
}

__device__ __forceinline__ void gll16(const void* g, void* l) {
  __builtin_amdgcn_global_load_lds(
      (const __attribute__((address_space(1))) void*)g,
      (__attribute__((address_space(3))) void*)l, 16, 0, 0);
}

// ---------------------------------------------------------------------------
// K0+K1 merged. build_w blocks FIRST (long-running, must dispatch early):
//   blocks [0, 832):     basis columns e_j -> W2[j][2m+c] bf16 (LDS ping-pong)
//   blocks [832, 7232):  X f32 [16384][784] -> Xb bf16 [16384][800]
// ---------------------------------------------------------------------------
__global__ __launch_bounds__(256) void prep(const float* __restrict__ X,
                                            unsigned* __restrict__ Xb,
                                            const float* __restrict__ w,
                                            unsigned* __restrict__ W2u) {
  __shared__ f32x4 UL4[NGATES];
  __shared__ f32x2 S0[DIM];
  __shared__ f32x2 S1[DIM];

  const int tid = threadIdx.x;

  if (blockIdx.x >= 832) {
    // ---- xcvt part ----
    const int cid = (blockIdx.x - 832) * 256 + tid;   // 16384*100 chunk tasks
    const int row = cid / 100, c8 = cid - row * 100;
    u32x4 out;
    if (c8 < 98) {
      const float* src = X + (size_t)row * IN_DIM + c8 * 8;
      f32x4 v0 = *(const f32x4*)src;
      f32x4 v1 = *(const f32x4*)(src + 4);
      out = u32x4{cvtpk(v0.x, v0.y), cvtpk(v0.z, v0.w),
                  cvtpk(v1.x, v1.y), cvtpk(v1.z, v1.w)};
    } else {
      out = u32x4{0, 0, 0, 0};
    }
    *(u32x4*)(Xb + (size_t)row * (KPAD / 2) + c8 * 4) = out;
    return;
  }

  // ---- build_w part (verified r6-r10) ----
  if (tid < NGATES) {
    // qml.Rot(phi, theta, omega) = RZ(omega) RY(theta) RZ(phi)
    float phi = w[tid * 3 + 0], th = w[tid * 3 + 1], om = w[tid * 3 + 2];
    float ct = cosf(th * 0.5f), st = sinf(th * 0.5f);
    float aa = (phi + om) * 0.5f, bb = (phi - om) * 0.5f;
    float cA = cosf(aa), sA = sinf(aa), cB = cosf(bb), sB = sinf(bb);
    // u00 = e^{-ia} c ; u01 = -e^{+ib} s  (u11 = conj(u00), u10 = -conj(u01))
    UL4[tid] = f32x4{ ct * cA, -ct * sA, -st * cB, -st * sB };
  }

  const int j = blockIdx.x;                     // 0..831
  unsigned* rowp = W2u + (size_t)j * 1024;

  if (j >= IN_DIM) {                            // zero pad rows (uniform branch)
#pragma unroll
    for (int k = 0; k < 4; ++k) rowp[tid + k * 256] = 0u;
    return;
  }

#pragma unroll
  for (int k = 0; k < 4; ++k) {
    const int m = tid + k * 256;
    S0[m] = f32x2{(m == j) ? 1.0f : 0.0f, 0.0f};
  }
  __syncthreads();

  for (int g = 0; g < NGATES; ++g) {
    const f32x2* src = (g & 1) ? S1 : S0;
    f32x2* dst = (g & 1) ? S0 : S1;
    const f32x4 A = UL4[g];
    const unsigned v = d_MT.v[g];
    const unsigned p = d_MT.p[g];
#pragma unroll
    for (int k = 0; k < 4; ++k) {
      const int m = tid + k * 256;
      f32x2 o = src[m];
      f32x2 q = src[m ^ (int)p];
      const unsigned sg = (unsigned)(__popc((int)((unsigned)m & v)) & 1) << 31;
      const f32x2 co = {A.x, fxor(A.y, sg)};
      const f32x2 cp = {fxor(A.z, sg), A.w};
      dst[m] = ampfma(o, q, co, cp);
    }
    __syncthreads();
  }

  const f32x2* fin = S0;   // 50 gates (even) -> final state back in S0
#pragma unroll
  for (int k = 0; k < 4; ++k) {
    const int m = tid + k * 256;
    f32x2 a = fin[m];
    rowp[m] = bf16pack(a.x, a.y);
  }
}

// ---------------------------------------------------------------------------
// K2: transpose W2 [832][2048] -> W2T [2048][832] (bf16), 64x64 tiles.
// ---------------------------------------------------------------------------
__global__ __launch_bounds__(256) void transpose_w(const unsigned* __restrict__ W2u,
                                                   unsigned* __restrict__ W2Tu) {
  __shared__ unsigned tile[64][33];
  const int j0 = blockIdx.x * 64;   // gridDim.x = 13
  const int n0 = blockIdx.y * 64;   // gridDim.y = 32
  const int t = threadIdx.x;
#pragma unroll
  for (int i = 0; i < 8; ++i) {
    const int idx = i * 256 + t;
    const int jr = idx >> 5, nc = idx & 31;
    tile[jr][nc] = W2u[(size_t)(j0 + jr) * 1024 + (n0 >> 1) + nc];
  }
  __syncthreads();
#pragma unroll
  for (int i = 0; i < 8; ++i) {
    const int idx = i * 256 + t;
    const int nr = idx >> 5, jc = idx & 31;
    const unsigned lo = tile[jc * 2][nr >> 1];
    const unsigned hi = tile[jc * 2 + 1][nr >> 1];
    const unsigned sh = (unsigned)(nr & 1) * 16u;
    const unsigned val = ((lo >> sh) & 0xffffu) | (((hi >> sh) & 0xffffu) << 16);
    W2Tu[(size_t)(n0 + nr) * (KALLOC / 2) + (j0 >> 1) + jc] = val;
  }
}

// ---------------------------------------------------------------------------
// K3 v9: fused GEMM + readout. 256x256 tile, 4 FAT waves (2x2 of 128x128
// each, 64 MFMA per wave-step), BK=32, double-buffered 64KB LDS -> 2 blocks
// per CU (launch_bounds(256,2)): inter-block TLP fills each block's barrier
// drain (m114) while keeping 256-tile intensity. m97-style sync: stage(t+1)
// issued first, frag reads, MFMA, one __syncthreads per step. Staging/frag
// swizzle formulas verified r6-r10 (SQ_LDS_BANK_CONFLICT == 0).
// ---------------------------------------------------------------------------
__global__ __launch_bounds__(256, 2) void gemm_fused(
    const unsigned short* __restrict__ Xb,
    const unsigned short* __restrict__ W2T,
    float* __restrict__ accb) {
  __shared__ u32x4 lds4[4096];   // 64 KB: 2 x (A 16KB + B 16KB)
  char* lds = (char*)lds4;

  const int tid = threadIdx.x;
  const int orig = blockIdx.x;                    // 512 blocks
  const int bx = (orig & 7) * 64 + (orig >> 3);   // XCD-chunked (512%8==0)
  const int mb = bx >> 3, nb = bx & 7;            // 64 mb x 8 nb
  const int m0 = mb * 256, n0 = nb * 256;
  const int lane = tid & 63, wv = tid >> 6;       // 4 waves
  const int wm = wv >> 1, wn = wv & 1;            // 2x2 of 128x128

  // stage lane geometry (verified r6-r10): lane l of unit g covers LDS row
  // g*16 + (l>>2), chunk' = l&3, from global chunk c = (l&3) ^ ((l>>3)&3).
  const int lrow = lane >> 2;
  const int lc = (lane & 3) ^ ((lane >> 3) & 3);

  auto stage = [&](int t) {
    char* Ab = lds + (t & 1) * 32768;
    char* Bb = Ab + 16384;
#pragma unroll
    for (int i = 0; i < 4; ++i) {                 // A: 4 units/wave (16 total)
      const int g = wv * 4 + i;
      const int row = g * 16 + lrow;
      gll16(Xb + (size_t)(m0 + row) * KPAD + t * 32 + lc * 8, Ab + g * 1024);
    }
#pragma unroll
    for (int i = 0; i < 4; ++i) {                 // B: 4 units/wave
      const int g = wv * 4 + i;
      const int row = g * 16 + lrow;
      gll16(W2T + (size_t)(n0 + row) * KALLOC + t * 32 + lc * 8, Bb + g * 1024);
    }
  };

  stage(0);
  __syncthreads();                                // tile0 landed (vmcnt drain)

  f32x4 acc[8][8];
#pragma unroll
  for (int fm = 0; fm < 8; ++fm)
#pragma unroll
    for (int fn = 0; fn < 8; ++fn) acc[fm][fn] = f32x4{0, 0, 0, 0};

  for (int t = 0; t < NK; ++t) {
    const char* Ab = lds + (t & 1) * 32768;
    const char* Bb = Ab + 16384;
    const int kc = lane >> 4;                     // k-chunk 0..3

    if (t < NK - 1) stage(t + 1);                 // -> other buffer, early

    bf16x8 af[8], bfr[8];
#pragma unroll
    for (int f = 0; f < 8; ++f) {
      const int ar = wm * 128 + f * 16 + (lane & 15);
      af[f] = *(const bf16x8*)(Ab + ar * 64 + ((kc ^ ((ar >> 1) & 3)) * 16));
      const int br = wn * 128 + f * 16 + (lane & 15);
      bfr[f] = *(const bf16x8*)(Bb + br * 64 + ((kc ^ ((br >> 1) & 3)) * 16));
    }

#pragma unroll
    for (int fm = 0; fm < 8; ++fm)
#pragma unroll
      for (int fn = 0; fn < 8; ++fn)
        acc[fm][fn] = __builtin_amdgcn_mfma_f32_16x16x32_bf16(
            af[fm], bfr[fn], acc[fm][fn], 0, 0, 0);

    __syncthreads();   // drains vmcnt (next tile ready) + all reads done
  }

  // ---- epilogue: per-sample (n2, z0, z1) partials (verified r4-r10) ----
  constexpr unsigned vz0 = MT.vz0, vz1 = MT.vz1;
  const int colbase = n0 + wn * 128 + (lane & 15);
#pragma unroll
  for (int fm = 0; fm < 8; ++fm) {
    float sn[4] = {0, 0, 0, 0}, s0[4] = {0, 0, 0, 0}, s1[4] = {0, 0, 0, 0};
#pragma unroll
    for (int fn = 0; fn < 8; ++fn) {
      const int st = (colbase + fn * 16) >> 1;     // quantum state index
      const float g0 = 1.0f - 2.0f * (float)(__popc(st & (int)vz0) & 1);
      const float g1 = 1.0f - 2.0f * (float)(__popc(st & (int)vz1) & 1);
#pragma unroll
      for (int r = 0; r < 4; ++r) {
        const float vv = acc[fm][fn][r];
        const float wq = vv * vv;
        sn[r] += wq;
        s0[r] = fmaf(g0, wq, s0[r]);
        s1[r] = fmaf(g1, wq, s1[r]);
      }
    }
#pragma unroll
    for (int off = 1; off < 16; off <<= 1) {
#pragma unroll
      for (int r = 0; r < 4; ++r) {
        sn[r] += __shfl_xor(sn[r], off);
        s0[r] += __shfl_xor(s0[r], off);
        s1[r] += __shfl_xor(s1[r], off);
      }
    }
    if ((lane & 15) == 0) {
#pragma unroll
      for (int r = 0; r < 4; ++r) {
        const int m = m0 + wm * 128 + fm * 16 + (lane >> 4) * 4 + r;
        *(f32x4*)(accb + ((size_t)nb * BATCH + m) * 4) =
            f32x4{sn[r], s0[r], s1[r], 0.0f};
      }
    }
  }
}

// ---------------------------------------------------------------------------
// K4/K5: per-sample loss + mean reduction.
// ---------------------------------------------------------------------------
__global__ __launch_bounds__(256) void loss_partial(const float* __restrict__ accb,
                                                    const int* __restrict__ y,
                                                    float* __restrict__ partial) {
  const int s = blockIdx.x * 256 + threadIdx.x;
  float n2 = 0.0f, z0 = 0.0f, z1 = 0.0f;
#pragma unroll
  for (int nb = 0; nb < 8; ++nb) {
    f32x4 v = *(const f32x4*)(accb + ((size_t)nb * BATCH + s) * 4);
    n2 += v.x; z0 += v.y; z1 += v.z;
  }
  const float inv = 1.0f / n2;
  const float l0 = z0 * inv, l1 = z1 * inv;
  const float mx = fmaxf(l0, l1);
  const float lse = mx + logf(expf(l0 - mx) + expf(l1 - mx));
  float loss = lse - ((y[s] == 0) ? l0 : l1);

  __shared__ float sm[256];
  sm[threadIdx.x] = loss;
  __syncthreads();
  for (int st = 128; st > 0; st >>= 1) {
    if (threadIdx.x < st) sm[threadIdx.x] += sm[threadIdx.x + st];
    __syncthreads();
  }
  if (threadIdx.x == 0) partial[blockIdx.x] = sm[0];
}

__global__ __launch_bounds__(64) void loss_final(const float* __restrict__ partial,
                                                 float* __restrict__ out) {
  float v = partial[threadIdx.x];
#pragma unroll
  for (int off = 1; off < 64; off <<= 1) v += __shfl_xor(v, off);
  if (threadIdx.x == 0) out[0] = v * (1.0f / (float)BATCH);
}

// ---------------------------------------------------------------------------
extern "C" void kernel_launch(void* const* d_in, const int* in_sizes, int n_in,
                              void* d_out, int out_size, void* d_ws, size_t ws_size,
                              hipStream_t stream) {
  const float* x = (const float*)d_in[0];   // [16384, 784] f32
  const float* w = (const float*)d_in[1];   // [5, 10, 3] f32
  const int*   y = (const int*)d_in[2];     // [16384] i32

  char* ws = (char*)d_ws;
  unsigned* Xb   = (unsigned*)ws;                    // 16384*800*2 = 26.2 MB
  unsigned* W2u  = (unsigned*)(ws + 26214400);       // 832*1024*4  = 3.41 MB
  unsigned* W2Tu = (unsigned*)(ws + 29622272);       // 2048*832*2  = 3.41 MB
  // after transpose_w, W2u region is dead -> reuse for accb (2 MB)
  float*    accb = (float*)(ws + 26214400);          // 8*16384*4 f32 = 2 MB
  float* partial = (float*)(ws + 33030144);          // 64 f32

  prep<<<7232, 256, 0, stream>>>(x, Xb, w, W2u);
  transpose_w<<<dim3(13, 32), 256, 0, stream>>>(W2u, W2Tu);
  gemm_fused<<<512, 256, 0, stream>>>((const unsigned short*)Xb,
                                      (const unsigned short*)W2Tu, accb);
  loss_partial<<<BATCH / 256, 256, 0, stream>>>(accb, y, partial);
  loss_final<<<1, 64, 0, stream>>>(partial, (float*)d_out);
}

// Round 12
// 104.257 us; speedup vs baseline: 2.6372x; 2.6372x over previous
//
#include <hip/hip_runtime.h>
#include <type_traits>

#define NQ 10
#define N_DEPTH 5
#define DIM 1024
#define BATCH 16384
#define IN_DIM 784
#define NGATES 50
#define KPAD 800      // Xb row length (bf16), cols 784..799 zero
#define KALLOC 832    // W2T row length = 13*64; W2 rows >=784 zero
#define NT 13         // K-tiles of 64 (13*64 = 832)

typedef float f32x2 __attribute__((ext_vector_type(2)));
typedef float f32x4 __attribute__((ext_vector_type(4)));
typedef short bf16x8 __attribute__((ext_vector_type(8)));
typedef unsigned u32x4 __attribute__((ext_vector_type(4)));

// ---------------------------------------------------------------------------
// Compile-time mask tables: CNOTs absorbed into GF(2)-linear index transform.
// ---------------------------------------------------------------------------
struct MaskTab {
  unsigned v[NGATES];
  unsigned p[NGATES];
  unsigned vz0, vz1;
};

constexpr MaskTab make_masks() {
  MaskTab t{};
  unsigned v[NQ], p[NQ];
  for (int i = 0; i < NQ; ++i) { v[i] = 1u << (9 - i); p[i] = 1u << (9 - i); }
  for (int d = 0; d < N_DEPTH; ++d) {
    for (int i = 0; i < NQ; ++i) {
      int c = i, tt = (i + 1) % NQ;
      v[tt] ^= v[c];
      p[c]  ^= p[tt];
    }
    for (int i = 0; i < NQ; ++i) {
      t.v[d * NQ + i] = v[i];
      t.p[d * NQ + i] = p[i];
    }
  }
  t.vz0 = v[0];
  t.vz1 = v[1];
  return t;
}

constexpr MaskTab MT = make_masks();
__constant__ MaskTab d_MT = make_masks();

// d = co*o + cp*q (complex), packed (re,im); 4 VOP3P instrs (verified r2-r11).
__device__ __forceinline__ f32x2 ampfma(f32x2 o, f32x2 q, f32x2 co, f32x2 cp) {
  f32x2 d;
  asm("v_pk_mul_f32 %0, %2, %1 op_sel:[0,0] op_sel_hi:[0,1]\n\t"
      "v_pk_fma_f32 %0, %2, %1, %0 op_sel:[1,1,0] op_sel_hi:[1,0,1] neg_lo:[1,0,0]\n\t"
      "v_pk_fma_f32 %0, %3, %4, %0 op_sel:[0,0,0] op_sel_hi:[0,1,1]\n\t"
      "v_pk_fma_f32 %0, %3, %4, %0 op_sel:[1,1,0] op_sel_hi:[1,0,1] neg_lo:[1,0,0]"
      : "=&v"(d)
      : "v"(o), "v"(co), "v"(cp), "v"(q));
  return d;
}

__device__ __forceinline__ float fxor(float x, unsigned m) {
  return __uint_as_float(__float_as_uint(x) ^ m);
}

__device__ __forceinline__ unsigned bf16pack(float lo, float hi) {
  unsigned a = __float_as_uint(lo), b = __float_as_uint(hi);
  unsigned ra = (a + 0x7fffu + ((a >> 16) & 1u)) >> 16;   // RNE
  unsigned rb = (b + 0x7fffu + ((b >> 16) & 1u)) >> 16;
  return (ra & 0xffffu) | (rb << 16);
}

__device__ __forceinline__ unsigned cvtpk(float a, float b) {
  unsigned d;
  asm("v_cvt_pk_bf16_f32 %0, %1, %2" : "=v"(d) : "v"(a), "v"(b));
  return d;
}

__device__ __forceinline__ void gll16(const void* g, void* l) {
  __builtin_amdgcn_global_load_lds(
      (const __attribute__((address_space(1))) void*)g,
      (__attribute__((address_space(3))) void*)l, 16, 0, 0);
}

// ---------------------------------------------------------------------------
// K0+K1 merged. build_w blocks FIRST (long-running, must dispatch early):
//   blocks [0, 832):     basis columns e_j -> W2[j][2m+c] bf16 (LDS ping-pong)
//   blocks [832, 7232):  X f32 [16384][784] -> Xb bf16 [16384][800]
// (verified r8)
// ---------------------------------------------------------------------------
__global__ __launch_bounds__(256) void prep(const float* __restrict__ X,
                                            unsigned* __restrict__ Xb,
                                            const float* __restrict__ w,
                                            unsigned* __restrict__ W2u) {
  __shared__ f32x4 UL4[NGATES];
  __shared__ f32x2 S0[DIM];
  __shared__ f32x2 S1[DIM];

  const int tid = threadIdx.x;

  if (blockIdx.x >= 832) {
    // ---- xcvt part ----
    const int cid = (blockIdx.x - 832) * 256 + tid;   // 16384*100 chunk tasks
    const int row = cid / 100, c8 = cid - row * 100;
    u32x4 out;
    if (c8 < 98) {
      const float* src = X + (size_t)row * IN_DIM + c8 * 8;
      f32x4 v0 = *(const f32x4*)src;
      f32x4 v1 = *(const f32x4*)(src + 4);
      out = u32x4{cvtpk(v0.x, v0.y), cvtpk(v0.z, v0.w),
                  cvtpk(v1.x, v1.y), cvtpk(v1.z, v1.w)};
    } else {
      out = u32x4{0, 0, 0, 0};
    }
    *(u32x4*)(Xb + (size_t)row * (KPAD / 2) + c8 * 4) = out;
    return;
  }

  // ---- build_w part (verified r6-r10) ----
  if (tid < NGATES) {
    // qml.Rot(phi, theta, omega) = RZ(omega) RY(theta) RZ(phi)
    float phi = w[tid * 3 + 0], th = w[tid * 3 + 1], om = w[tid * 3 + 2];
    float ct = cosf(th * 0.5f), st = sinf(th * 0.5f);
    float aa = (phi + om) * 0.5f, bb = (phi - om) * 0.5f;
    float cA = cosf(aa), sA = sinf(aa), cB = cosf(bb), sB = sinf(bb);
    // u00 = e^{-ia} c ; u01 = -e^{+ib} s  (u11 = conj(u00), u10 = -conj(u01))
    UL4[tid] = f32x4{ ct * cA, -ct * sA, -st * cB, -st * sB };
  }

  const int j = blockIdx.x;                     // 0..831
  unsigned* rowp = W2u + (size_t)j * 1024;

  if (j >= IN_DIM) {                            // zero pad rows (uniform branch)
#pragma unroll
    for (int k = 0; k < 4; ++k) rowp[tid + k * 256] = 0u;
    return;
  }

#pragma unroll
  for (int k = 0; k < 4; ++k) {
    const int m = tid + k * 256;
    S0[m] = f32x2{(m == j) ? 1.0f : 0.0f, 0.0f};
  }
  __syncthreads();

  for (int g = 0; g < NGATES; ++g) {
    const f32x2* src = (g & 1) ? S1 : S0;
    f32x2* dst = (g & 1) ? S0 : S1;
    const f32x4 A = UL4[g];
    const unsigned v = d_MT.v[g];
    const unsigned p = d_MT.p[g];
#pragma unroll
    for (int k = 0; k < 4; ++k) {
      const int m = tid + k * 256;
      f32x2 o = src[m];
      f32x2 q = src[m ^ (int)p];
      const unsigned sg = (unsigned)(__popc((int)((unsigned)m & v)) & 1) << 31;
      const f32x2 co = {A.x, fxor(A.y, sg)};
      const f32x2 cp = {fxor(A.z, sg), A.w};
      dst[m] = ampfma(o, q, co, cp);
    }
    __syncthreads();
  }

  const f32x2* fin = S0;   // 50 gates (even) -> final state back in S0
#pragma unroll
  for (int k = 0; k < 4; ++k) {
    const int m = tid + k * 256;
    f32x2 a = fin[m];
    rowp[m] = bf16pack(a.x, a.y);
  }
}

// ---------------------------------------------------------------------------
// K2: transpose W2 [832][2048] -> W2T [2048][832] (bf16), 64x64 tiles.
// (verified r4-r10)
// ---------------------------------------------------------------------------
__global__ __launch_bounds__(256) void transpose_w(const unsigned* __restrict__ W2u,
                                                   unsigned* __restrict__ W2Tu) {
  __shared__ unsigned tile[64][33];
  const int j0 = blockIdx.x * 64;   // gridDim.x = 13
  const int n0 = blockIdx.y * 64;   // gridDim.y = 32
  const int t = threadIdx.x;
#pragma unroll
  for (int i = 0; i < 8; ++i) {
    const int idx = i * 256 + t;
    const int jr = idx >> 5, nc = idx & 31;
    tile[jr][nc] = W2u[(size_t)(j0 + jr) * 1024 + (n0 >> 1) + nc];
  }
  __syncthreads();
#pragma unroll
  for (int i = 0; i < 8; ++i) {
    const int idx = i * 256 + t;
    const int nr = idx >> 5, jc = idx & 31;
    const unsigned lo = tile[jc * 2][nr >> 1];
    const unsigned hi = tile[jc * 2 + 1][nr >> 1];
    const unsigned sh = (unsigned)(nr & 1) * 16u;
    const unsigned val = ((lo >> sh) & 0xffffu) | (((hi >> sh) & 0xffffu) << 16);
    W2Tu[(size_t)(n0 + nr) * (KALLOC / 2) + (j0 >> 1) + jc] = val;
  }
}

// ---------------------------------------------------------------------------
// K3 v10: fused GEMM + readout. 256x256 tile, 8 waves (2M x 4N, 128x64/wave),
// BK=64 -> 13 K-tiles (25->13 barriers: amortize the per-step fixed overhead
// that r8-r9 showed dominates). LDS 2 x (A 32KB + B 32KB) = 128KB dbuf.
// One barrier per tile (r8-proven loop shape): kh0 reads -> stage(t+1) ->
// kh1 reads (overlap kh0's MFMA via counted lgkm) -> MFMA kh0 -> MFMA kh1 ->
// vmcnt(0) -> barrier. 128B rows, 8-chunk XOR swizzle: phys chunk =
// c ^ (row&7) (bijective per row; 8 rows span all 32 banks -> 2-way free).
// A-tail: source col clamped to 792 for k>=800; those j pair with zero B rows.
// ---------------------------------------------------------------------------
__global__ __launch_bounds__(512) void gemm_fused(const unsigned short* __restrict__ Xb,
                                                  const unsigned short* __restrict__ W2T,
                                                  float* __restrict__ accb) {
  __shared__ u32x4 lds4[8192];   // 128 KB
  char* lds = (char*)lds4;

  const int tid = threadIdx.x;
  const int orig = blockIdx.x;                    // 512 blocks
  const int bx = (orig & 7) * 64 + (orig >> 3);   // XCD-chunked (512%8==0)
  const int mb = bx >> 3, nb = bx & 7;
  const int m0 = mb * 256, n0 = nb * 256;
  const int lane = tid & 63, wv = tid >> 6;
  const int wm = wv >> 2, wn = wv & 3;

  // stage lane geometry: unit g covers rows g*8..g*8+7 (128B rows).
  // lane l -> LDS (row_local = l>>3, chunk' = l&7); gll writes base+l*16
  // linearly; source global chunk c = (l&7) ^ ((l>>3)&7) so that phys
  // chunk' = c ^ (row&7).
  const int lrow = lane >> 3;                     // 0..7
  const int lc = (lane & 7) ^ lrow;               // source chunk 0..7

  auto stage = [&](int t) {
    char* Ab = lds + (t & 1) * 65536;
    char* Bb = Ab + 32768;
    int colA = t * 64 + lc * 8;
    if (colA > 792) colA = 792;                   // clamp: j>=800 pairs 0-B
    const int colB = t * 64 + lc * 8;
#pragma unroll
    for (int i = 0; i < 4; ++i) {                 // A: 4 units/wave (32 total)
      const int g = wv * 4 + i;
      const int row = g * 8 + lrow;
      gll16(Xb + (size_t)(m0 + row) * KPAD + colA, Ab + g * 1024);
    }
#pragma unroll
    for (int i = 0; i < 4; ++i) {                 // B: 4 units/wave
      const int g = wv * 4 + i;
      const int row = g * 8 + lrow;
      gll16(W2T + (size_t)(n0 + row) * KALLOC + colB, Bb + g * 1024);
    }
  };

  stage(0);
  asm volatile("s_waitcnt vmcnt(0)" ::: "memory");
  __builtin_amdgcn_s_barrier();

  f32x4 acc[8][4];
#pragma unroll
  for (int fm = 0; fm < 8; ++fm)
#pragma unroll
    for (int fn = 0; fn < 4; ++fn) acc[fm][fn] = f32x4{0, 0, 0, 0};

  const int kc = lane >> 4;                       // k-chunk-of-8 within K=32

  for (int t = 0; t < NT; ++t) {
    const char* Ab = lds + (t & 1) * 65536;
    const char* Bb = Ab + 32768;

    bf16x8 af0[8], bf0[4], af1[8], bf1[4];
    // kh=0 operand reads (12 ds_read_b128)
#pragma unroll
    for (int f = 0; f < 8; ++f) {
      const int ar = wm * 128 + f * 16 + (lane & 15);
      af0[f] = *(const bf16x8*)(Ab + ar * 128 + ((kc ^ (ar & 7)) * 16));
    }
#pragma unroll
    for (int f = 0; f < 4; ++f) {
      const int br = wn * 64 + f * 16 + (lane & 15);
      bf0[f] = *(const bf16x8*)(Bb + br * 128 + ((kc ^ (br & 7)) * 16));
    }
    if (t < NT - 1) stage(t + 1);                 // -> other buffer (safe)
    // kh=1 operand reads — overlap kh0's MFMA via counted lgkm waits
#pragma unroll
    for (int f = 0; f < 8; ++f) {
      const int ar = wm * 128 + f * 16 + (lane & 15);
      af1[f] = *(const bf16x8*)(Ab + ar * 128 + (((4 + kc) ^ (ar & 7)) * 16));
    }
#pragma unroll
    for (int f = 0; f < 4; ++f) {
      const int br = wn * 64 + f * 16 + (lane & 15);
      bf1[f] = *(const bf16x8*)(Bb + br * 128 + (((4 + kc) ^ (br & 7)) * 16));
    }

    __builtin_amdgcn_s_setprio(1);
#pragma unroll
    for (int fm = 0; fm < 8; ++fm)
#pragma unroll
      for (int fn = 0; fn < 4; ++fn)
        acc[fm][fn] = __builtin_amdgcn_mfma_f32_16x16x32_bf16(
            af0[fm], bf0[fn], acc[fm][fn], 0, 0, 0);
    __builtin_amdgcn_s_setprio(0);

    __builtin_amdgcn_s_setprio(1);
#pragma unroll
    for (int fm = 0; fm < 8; ++fm)
#pragma unroll
      for (int fn = 0; fn < 4; ++fn)
        acc[fm][fn] = __builtin_amdgcn_mfma_f32_16x16x32_bf16(
            af1[fm], bf1[fn], acc[fm][fn], 0, 0, 0);
    __builtin_amdgcn_s_setprio(0);

    if (t < NT - 1) {
      asm volatile("s_waitcnt vmcnt(0)" ::: "memory");  // next tile landed
      __builtin_amdgcn_sched_barrier(0);
      __builtin_amdgcn_s_barrier();
    }
  }

  // ---- epilogue: per-sample (n2, z0, z1) partials (verified r4-r9) ----
  constexpr unsigned vz0 = MT.vz0, vz1 = MT.vz1;
  const int colbase = n0 + wn * 64 + (lane & 15);
#pragma unroll
  for (int fm = 0; fm < 8; ++fm) {
    float sn[4] = {0, 0, 0, 0}, s0[4] = {0, 0, 0, 0}, s1[4] = {0, 0, 0, 0};
#pragma unroll
    for (int fn = 0; fn < 4; ++fn) {
      const int st = (colbase + fn * 16) >> 1;     // quantum state index
      const float g0 = 1.0f - 2.0f * (float)(__popc(st & (int)vz0) & 1);
      const float g1 = 1.0f - 2.0f * (float)(__popc(st & (int)vz1) & 1);
#pragma unroll
      for (int r = 0; r < 4; ++r) {
        const float vv = acc[fm][fn][r];
        const float wq = vv * vv;
        sn[r] += wq;
        s0[r] = fmaf(g0, wq, s0[r]);
        s1[r] = fmaf(g1, wq, s1[r]);
      }
    }
#pragma unroll
    for (int off = 1; off < 16; off <<= 1) {
#pragma unroll
      for (int r = 0; r < 4; ++r) {
        sn[r] += __shfl_xor(sn[r], off);
        s0[r] += __shfl_xor(s0[r], off);
        s1[r] += __shfl_xor(s1[r], off);
      }
    }
    if ((lane & 15) == 0) {
#pragma unroll
      for (int r = 0; r < 4; ++r) {
        const int m = m0 + wm * 128 + fm * 16 + (lane >> 4) * 4 + r;
        *(f32x4*)(accb + ((size_t)nb * BATCH + m) * 4) =
            f32x4{sn[r], s0[r], s1[r], 0.0f};
      }
    }
  }
}

// ---------------------------------------------------------------------------
// K4/K5: per-sample loss + mean reduction. (verified r8)
// ---------------------------------------------------------------------------
__global__ __launch_bounds__(256) void loss_partial(const float* __restrict__ accb,
                                                    const int* __restrict__ y,
                                                    float* __restrict__ partial) {
  const int s = blockIdx.x * 256 + threadIdx.x;
  float n2 = 0.0f, z0 = 0.0f, z1 = 0.0f;
#pragma unroll
  for (int nb = 0; nb < 8; ++nb) {
    f32x4 v = *(const f32x4*)(accb + ((size_t)nb * BATCH + s) * 4);
    n2 += v.x; z0 += v.y; z1 += v.z;
  }
  const float inv = 1.0f / n2;
  const float l0 = z0 * inv, l1 = z1 * inv;
  const float mx = fmaxf(l0, l1);
  const float lse = mx + logf(expf(l0 - mx) + expf(l1 - mx));
  float loss = lse - ((y[s] == 0) ? l0 : l1);

  __shared__ float sm[256];
  sm[threadIdx.x] = loss;
  __syncthreads();
  for (int st = 128; st > 0; st >>= 1) {
    if (threadIdx.x < st) sm[threadIdx.x] += sm[threadIdx.x + st];
    __syncthreads();
  }
  if (threadIdx.x == 0) partial[blockIdx.x] = sm[0];
}

__global__ __launch_bounds__(64) void loss_final(const float* __restrict__ partial,
                                                 float* __restrict__ out) {
  float v = partial[threadIdx.x];
#pragma unroll
  for (int off = 1; off < 64; off <<= 1) v += __shfl_xor(v, off);
  if (threadIdx.x == 0) out[0] = v * (1.0f / (float)BATCH);
}

// ---------------------------------------------------------------------------
extern "C" void kernel_launch(void* const* d_in, const int* in_sizes, int n_in,
                              void* d_out, int out_size, void* d_ws, size_t ws_size,
                              hipStream_t stream) {
  const float* x = (const float*)d_in[0];   // [16384, 784] f32
  const float* w = (const float*)d_in[1];   // [5, 10, 3] f32
  const int*   y = (const int*)d_in[2];     // [16384] i32

  char* ws = (char*)d_ws;
  unsigned* Xb   = (unsigned*)ws;                    // 16384*800*2 = 26.2 MB
  unsigned* W2u  = (unsigned*)(ws + 26214400);       // 832*1024*4  = 3.41 MB
  unsigned* W2Tu = (unsigned*)(ws + 29622272);       // 2048*832*2  = 3.41 MB
  // after transpose_w, W2u region is dead -> reuse for accb (2 MB)
  float*    accb = (float*)(ws + 26214400);          // 8*16384*4 f32 = 2 MB
  float* partial = (float*)(ws + 33030144);          // 64 f32

  prep<<<7232, 256, 0, stream>>>(x, Xb, w, W2u);
  transpose_w<<<dim3(13, 32), 256, 0, stream>>>(W2u, W2Tu);
  gemm_fused<<<512, 512, 0, stream>>>((const unsigned short*)Xb,
                                      (const unsigned short*)W2Tu, accb);
  loss_partial<<<BATCH / 256, 256, 0, stream>>>(accb, y, partial);
  loss_final<<<1, 64, 0, stream>>>(partial, (float*)d_out);
}